// Round 10
// baseline (393.872 us; speedup 1.0000x reference)
//
#include <hip/hip_runtime.h>
#include <hip/hip_fp16.h>

// ---------------------------------------------------------------------------
// GCN: 2x GraphConv (norm='both') + FC.  fp32 math, fp16 intermediates.
// R2..R8: 5943 -> 325 us (CSR gather, fold FC, MFMA GEMMs, fp16, no atomics).
// R9: reservation partition (neutral).
// R10: (a) FUSE gather1+gemm40: block gathers 128 contiguous nodes' h1 rows
//          into an LDS tile (relu/bias in-register) and MFMAs vs W2p ->
//          eliminates the 51 MB h1 write+read round trip and a dispatch.
//      (b) fuse fine_dst+fine_src; fuse init_cursors+fold_w2 (9 -> 6 disp).
//      (c) CHUNK 4096 for partition load balance.
// gather1's 178 MB FETCH = 8 XCDs x 22 MB compulsory L2 misses (random graph,
// per-XCD private L2) at the ~3 TB/s miss-path ceiling: structural floor.
// ---------------------------------------------------------------------------

#define CHUNK    4096   // edges per partition block
#define NB       256    // coarse buckets (node>>9; ceil(100000/512)=196)
#define SLAB     9216   // per-bucket slab capacity (mean 8163 + ~11 sigma)

typedef __attribute__((ext_vector_type(8))) short bf16x8;
typedef __attribute__((ext_vector_type(4))) float f32x4;

struct __align__(8)  half4 { __half x, y, z, w; };
struct __align__(16) half8 { __half h[8]; };

__device__ __forceinline__ void acc_half4(float4& acc, const half4 v) {
    acc.x += __half2float(v.x);
    acc.y += __half2float(v.y);
    acc.z += __half2float(v.z);
    acc.w += __half2float(v.w);
}

__device__ __forceinline__ unsigned short f2bf(float f) {
    union { float f; unsigned u; } v; v.f = f;
    unsigned r = v.u + 0x7FFFu + ((v.u >> 16) & 1u);   // RNE
    return (unsigned short)(r >> 16);
}
__device__ __forceinline__ float bf2f(unsigned short h) {
    union { unsigned u; float f; } v; v.u = ((unsigned)h) << 16;
    return v.f;
}

// setup: W2p = W2@Wfc, b2p = b2@Wfc + bfc, and slab cursor init
__global__ void setup_kernel(const float* __restrict__ W2, const float* __restrict__ Wfc,
                             const float* __restrict__ b2, const float* __restrict__ bfc,
                             float* __restrict__ W2p, float* __restrict__ b2p,
                             int* __restrict__ cur_d, int* __restrict__ cur_s, int nbuck) {
    int idx = blockIdx.x * blockDim.x + threadIdx.x;
    if (idx < nbuck) { cur_d[idx] = idx * SLAB; cur_s[idx] = idx * SLAB; }
    if (idx < 128 * 40) {
        int k = idx / 40, c = idx - k * 40;
        const float* w2row = W2 + k * 128;
        float a = 0.f;
        #pragma unroll 8
        for (int j = 0; j < 128; ++j) a += w2row[j] * Wfc[j * 40 + c];
        W2p[idx] = a;
    } else if (idx < 129 * 40) {
        int c = idx - 128 * 40;
        float a = bfc[c];
        #pragma unroll 8
        for (int j = 0; j < 128; ++j) a += b2[j] * Wfc[j * 40 + c];
        b2p[c] = a;
    }
}

// ------------- single-pass partition with per-bucket slab reservation -------
__global__ __launch_bounds__(256) void scatter_res_kernel(
        const int* __restrict__ src, const int* __restrict__ dst,
        int* __restrict__ cur_d, int* __restrict__ cur_s,
        unsigned int* __restrict__ ppack, unsigned short* __restrict__ es_loc,
        int E) {
    __shared__ int hd[NB], hs[NB], bd[NB], bs[NB];
    const int tid = threadIdx.x;
    hd[tid] = 0; hs[tid] = 0;
    __syncthreads();
    const int base = blockIdx.x * CHUNK;
    const int end  = min(base + CHUNK, E);
    for (int e = base + tid; e < end; e += 256) {
        atomicAdd(&hd[((unsigned)dst[e]) >> 9], 1);
        atomicAdd(&hs[((unsigned)src[e]) >> 9], 1);
    }
    __syncthreads();
    int cd = hd[tid], cs = hs[tid];
    bd[tid] = cd ? atomicAdd(&cur_d[tid], cd) : 0;
    bs[tid] = cs ? atomicAdd(&cur_s[tid], cs) : 0;
    hd[tid] = 0; hs[tid] = 0;
    __syncthreads();
    for (int e = base + tid; e < end; e += 256) {
        int d = dst[e], s = src[e];
        unsigned bin_d = ((unsigned)d) >> 9;
        int pos = bd[bin_d] + atomicAdd(&hd[bin_d], 1);
        ppack[pos] = (((unsigned)d & 511u) << 17) | (unsigned)s;
        unsigned bin_s = ((unsigned)s) >> 9;
        int ps = bs[bin_s] + atomicAdd(&hs[bin_s], 1);
        es_loc[ps] = (unsigned short)(s & 511);
    }
}

// ------------- per-bucket fine pass: dst (deg/norm/row_ptr/csr) + src (norm_out)
__global__ __launch_bounds__(256) void fine_kernel(
        const unsigned int* __restrict__ ppack, const unsigned short* __restrict__ es_loc,
        const int* __restrict__ cur_d, const int* __restrict__ cur_s,
        int* __restrict__ deg_in, float* __restrict__ norm_in,
        int* __restrict__ row_ptr, int* __restrict__ csr_src,
        float* __restrict__ norm_out, int N_) {
    __shared__ int h[512];
    __shared__ int psum[256];
    const int tid = threadIdx.x;
    const int b = blockIdx.x;
    const int start = b * SLAB;
    const int node0 = b * 512;

    // ---- dst side ----
    const int end_d = cur_d[b];
    h[tid] = 0; h[tid + 256] = 0;
    __syncthreads();
    for (int i = start + tid; i < end_d; i += 256)
        atomicAdd(&h[ppack[i] >> 17], 1);
    __syncthreads();

    int a0 = h[2 * tid], a1 = h[2 * tid + 1];
    int pair = a0 + a1;
    psum[tid] = pair;
    __syncthreads();
    for (int off = 1; off < 256; off <<= 1) {
        int t = (tid >= off) ? psum[tid - off] : 0;
        __syncthreads();
        psum[tid] += t;
        __syncthreads();
    }
    int base0 = psum[tid] - pair + start;   // slab-local CSR position

    int n0 = node0 + 2 * tid, n1 = n0 + 1;
    if (n0 < N_) {
        deg_in[n0]  = a0;
        row_ptr[n0] = base0;
        norm_in[n0] = rsqrtf((float)(a0 < 1 ? 1 : a0));
    }
    if (n1 < N_) {
        deg_in[n1]  = a1;
        row_ptr[n1] = base0 + a0;
        norm_in[n1] = rsqrtf((float)(a1 < 1 ? 1 : a1));
    }
    h[2 * tid]     = base0;
    h[2 * tid + 1] = base0 + a0;
    __syncthreads();

    for (int i = start + tid; i < end_d; i += 256) {
        unsigned int pk = ppack[i];
        int pos = atomicAdd(&h[pk >> 17], 1);
        csr_src[pos] = (int)(pk & 0x1FFFFu);
    }
    __syncthreads();

    // ---- src side ----
    const int end_s = cur_s[b];
    h[tid] = 0; h[tid + 256] = 0;
    __syncthreads();
    for (int i = start + tid; i < end_s; i += 256)
        atomicAdd(&h[es_loc[i]], 1);
    __syncthreads();

    n0 = node0 + tid; n1 = n0 + 256;
    if (n0 < N_) { int d = h[tid];       norm_out[n0] = rsqrtf((float)(d < 1 ? 1 : d)); }
    if (n1 < N_) { int d = h[tid + 256]; norm_out[n1] = rsqrtf((float)(d < 1 ? 1 : d)); }
}

// ---------------------------------------------------------------------------
// Y[nrows x 128] (fp16) = (X * scale[row]) @ W[128x128]  via MFMA bf16 split.
// ---------------------------------------------------------------------------
__global__ __launch_bounds__(256, 2) void gemm128(
        const float* __restrict__ X, const float* __restrict__ scale,
        const float* __restrict__ W, __half* __restrict__ Y, int nrows) {
    __shared__ unsigned short wsh[128 * 128];   // 32 KB, frag-ordered bf16 hi
    __shared__ unsigned short wsl[128 * 128];   // 32 KB, frag-ordered bf16 lo
    const int tid = threadIdx.x;

    for (int i = tid; i < 4096; i += 256) {
        int k  = i >> 5;
        int n0 = (i & 31) * 4;
        float4 wv = *(const float4*)(W + k * 128 + n0);
        int q = k >> 5, j = k & 7, lb = ((k >> 3) & 3) * 16;
        int tcol = n0 >> 4;
        int base = ((tcol * 4 + q) * 64) * 8 + j;
        float vals[4] = {wv.x, wv.y, wv.z, wv.w};
        #pragma unroll
        for (int c = 0; c < 4; ++c) {
            int l = lb + ((n0 + c) & 15);
            unsigned short h = f2bf(vals[c]);
            wsh[base + l * 8] = h;
            wsl[base + l * 8] = f2bf(vals[c] - bf2f(h));
        }
    }
    __syncthreads();

    const int lane = tid & 63;
    const int w    = tid >> 6;
    const int m    = lane & 15;
    const int quad = lane >> 4;
    const int rowBase = blockIdx.x * 128 + w * 32;

    bf16x8 Ah[2][4], Al[2][4];
    #pragma unroll
    for (int rt = 0; rt < 2; ++rt) {
        int r = rowBase + rt * 16 + m;
        float sc = (r < nrows) ? scale[r] : 0.f;
        const float* xr = X + (size_t)(r < nrows ? r : 0) * 128;
        #pragma unroll
        for (int q = 0; q < 4; ++q) {
            int k0 = q * 32 + quad * 8;
            float4 a = *(const float4*)(xr + k0);
            float4 bv = *(const float4*)(xr + k0 + 4);
            float v[8] = {a.x * sc, a.y * sc, a.z * sc, a.w * sc,
                          bv.x * sc, bv.y * sc, bv.z * sc, bv.w * sc};
            bf16x8 hi, lo;
            #pragma unroll
            for (int j = 0; j < 8; ++j) {
                unsigned short h = f2bf(v[j]);
                hi[j] = (short)h;
                lo[j] = (short)f2bf(v[j] - bf2f(h));
            }
            Ah[rt][q] = hi; Al[rt][q] = lo;
        }
    }

    f32x4 acc[2][8];
    #pragma unroll
    for (int rt = 0; rt < 2; ++rt)
        #pragma unroll
        for (int t = 0; t < 8; ++t)
            acc[rt][t] = (f32x4){0.f, 0.f, 0.f, 0.f};

    #pragma unroll
    for (int t = 0; t < 8; ++t) {
        #pragma unroll
        for (int q = 0; q < 4; ++q) {
            const int off = ((t * 4 + q) * 64 + lane) * 8;
            bf16x8 Bh = *(const bf16x8*)(wsh + off);
            bf16x8 Bl = *(const bf16x8*)(wsl + off);
            #pragma unroll
            for (int rt = 0; rt < 2; ++rt) {
                acc[rt][t] = __builtin_amdgcn_mfma_f32_16x16x32_bf16(Ah[rt][q], Bh, acc[rt][t], 0, 0, 0);
                acc[rt][t] = __builtin_amdgcn_mfma_f32_16x16x32_bf16(Ah[rt][q], Bl, acc[rt][t], 0, 0, 0);
                acc[rt][t] = __builtin_amdgcn_mfma_f32_16x16x32_bf16(Al[rt][q], Bh, acc[rt][t], 0, 0, 0);
            }
        }
    }

    #pragma unroll
    for (int rt = 0; rt < 2; ++rt) {
        int r0 = rowBase + rt * 16 + quad * 4;
        #pragma unroll
        for (int reg = 0; reg < 4; ++reg) {
            int r = r0 + reg;
            if (r >= nrows) continue;
            __half* yr = Y + (size_t)r * 128 + m;
            #pragma unroll
            for (int t = 0; t < 8; ++t)
                yr[t * 16] = __float2half(acc[rt][t][reg]);
        }
    }
}

// ---------------------------------------------------------------------------
// FUSED layer-2: for 128 contiguous nodes, gather h1 rows into an LDS tile
// (h1 = relu(sum H[src] * ni + b1)), then G = (h1 * norm_out) @ W2p via MFMA.
// tile layout [q][node][32] halfs: bank-clean for half4 writes and 16B A-reads.
// ---------------------------------------------------------------------------
__global__ __launch_bounds__(256, 2) void layer2_fused(
        const __half* __restrict__ H, const int* __restrict__ row_ptr,
        const int* __restrict__ deg, const int* __restrict__ csr_src,
        const float* __restrict__ norm_in, const float* __restrict__ b1,
        const float* __restrict__ norm_out, const float* __restrict__ Wp,
        __half* __restrict__ G, int n) {
    __shared__ unsigned short wsh[48 * 128];        // 12 KB
    __shared__ unsigned short wsl[48 * 128];        // 12 KB
    __shared__ __half tile[4][128][32];             // 32 KB: [q][node_local][col]
    const int tid = threadIdx.x;
    const int node0 = blockIdx.x * 128;

    // stage + split W2p (pad cols 40..47), fragment order
    for (int i = tid; i < 6144; i += 256) {
        int k  = i / 48;
        int nn = i - k * 48;
        float v = (nn < 40) ? Wp[k * 40 + nn] : 0.f;
        int t = nn >> 4, q = k >> 5, j = k & 7;
        int l = ((k >> 3) & 3) * 16 + (nn & 15);
        int base = ((t * 4 + q) * 64 + l) * 8 + j;
        unsigned short h = f2bf(v);
        wsh[base] = h;
        wsl[base] = f2bf(v - bf2f(h));
    }

    // ---- gather phase: 16 iterations x 8 nodes (32 lanes/node, half4/lane) ----
    const int c  = (tid & 31) * 4;         // col 0..124
    const int qc = c >> 5;                 // col group
    const int cc = c & 31;                 // col within group
    for (int it = 0; it < 16; ++it) {
        int nl   = it * 8 + (tid >> 5);    // node_local 0..127
        int node = node0 + nl;
        half4 o;
        if (node < n) {
            const int start = row_ptr[node];
            const int cnt   = deg[node];
            float4 acc = make_float4(0.f, 0.f, 0.f, 0.f);
            int j = 0;
            for (; j + 8 <= cnt; j += 8) {
                int s0 = csr_src[start + j];
                int s1 = csr_src[start + j + 1];
                int s2 = csr_src[start + j + 2];
                int s3 = csr_src[start + j + 3];
                int s4 = csr_src[start + j + 4];
                int s5 = csr_src[start + j + 5];
                int s6 = csr_src[start + j + 6];
                int s7 = csr_src[start + j + 7];
                half4 v0 = *(const half4*)(H + (long long)s0 * 128 + c);
                half4 v1 = *(const half4*)(H + (long long)s1 * 128 + c);
                half4 v2 = *(const half4*)(H + (long long)s2 * 128 + c);
                half4 v3 = *(const half4*)(H + (long long)s3 * 128 + c);
                half4 v4 = *(const half4*)(H + (long long)s4 * 128 + c);
                half4 v5 = *(const half4*)(H + (long long)s5 * 128 + c);
                half4 v6 = *(const half4*)(H + (long long)s6 * 128 + c);
                half4 v7 = *(const half4*)(H + (long long)s7 * 128 + c);
                acc_half4(acc, v0); acc_half4(acc, v1); acc_half4(acc, v2); acc_half4(acc, v3);
                acc_half4(acc, v4); acc_half4(acc, v5); acc_half4(acc, v6); acc_half4(acc, v7);
            }
            for (; j + 4 <= cnt; j += 4) {
                int s0 = csr_src[start + j];
                int s1 = csr_src[start + j + 1];
                int s2 = csr_src[start + j + 2];
                int s3 = csr_src[start + j + 3];
                half4 v0 = *(const half4*)(H + (long long)s0 * 128 + c);
                half4 v1 = *(const half4*)(H + (long long)s1 * 128 + c);
                half4 v2 = *(const half4*)(H + (long long)s2 * 128 + c);
                half4 v3 = *(const half4*)(H + (long long)s3 * 128 + c);
                acc_half4(acc, v0); acc_half4(acc, v1); acc_half4(acc, v2); acc_half4(acc, v3);
            }
            for (; j < cnt; ++j) {
                int s0 = csr_src[start + j];
                half4 v0 = *(const half4*)(H + (long long)s0 * 128 + c);
                acc_half4(acc, v0);
            }
            float ni = norm_in[node];
            float4 bb = *(const float4*)(b1 + c);
            o.x = __float2half(fmaxf(acc.x * ni + bb.x, 0.f));
            o.y = __float2half(fmaxf(acc.y * ni + bb.y, 0.f));
            o.z = __float2half(fmaxf(acc.z * ni + bb.z, 0.f));
            o.w = __float2half(fmaxf(acc.w * ni + bb.w, 0.f));
        } else {
            o.x = __float2half(0.f); o.y = o.x; o.z = o.x; o.w = o.x;
        }
        *(half4*)(&tile[qc][nl][cc]) = o;
    }
    __syncthreads();

    // ---- MFMA phase: G-tile = (h1_tile * norm_out) @ W2p ----
    const int lane = tid & 63;
    const int w    = tid >> 6;
    const int m    = lane & 15;
    const int quad = lane >> 4;
    const int rb   = w * 32;

    bf16x8 Ah[2][4], Al[2][4];
    #pragma unroll
    for (int rt = 0; rt < 2; ++rt) {
        int rl = rb + rt * 16 + m;
        int r  = node0 + rl;
        float sc = (r < n) ? norm_out[r] : 0.f;
        #pragma unroll
        for (int q = 0; q < 4; ++q) {
            half8 hv = *(const half8*)(&tile[q][rl][quad * 8]);
            bf16x8 hi, lo;
            #pragma unroll
            for (int j = 0; j < 8; ++j) {
                float v = __half2float(hv.h[j]) * sc;
                unsigned short h = f2bf(v);
                hi[j] = (short)h;
                lo[j] = (short)f2bf(v - bf2f(h));
            }
            Ah[rt][q] = hi; Al[rt][q] = lo;
        }
    }

    f32x4 acc[2][3];
    #pragma unroll
    for (int rt = 0; rt < 2; ++rt)
        #pragma unroll
        for (int t = 0; t < 3; ++t)
            acc[rt][t] = (f32x4){0.f, 0.f, 0.f, 0.f};

    #pragma unroll
    for (int t = 0; t < 3; ++t) {
        #pragma unroll
        for (int q = 0; q < 4; ++q) {
            const int off = ((t * 4 + q) * 64 + lane) * 8;
            bf16x8 Bh = *(const bf16x8*)(wsh + off);
            bf16x8 Bl = *(const bf16x8*)(wsl + off);
            #pragma unroll
            for (int rt = 0; rt < 2; ++rt) {
                acc[rt][t] = __builtin_amdgcn_mfma_f32_16x16x32_bf16(Ah[rt][q], Bh, acc[rt][t], 0, 0, 0);
                acc[rt][t] = __builtin_amdgcn_mfma_f32_16x16x32_bf16(Ah[rt][q], Bl, acc[rt][t], 0, 0, 0);
                acc[rt][t] = __builtin_amdgcn_mfma_f32_16x16x32_bf16(Al[rt][q], Bh, acc[rt][t], 0, 0, 0);
            }
        }
    }

    #pragma unroll
    for (int rt = 0; rt < 2; ++rt) {
        int r0 = node0 + rb + rt * 16 + quad * 4;
        #pragma unroll
        for (int reg = 0; reg < 4; ++reg) {
            int r = r0 + reg;
            if (r >= n) continue;
            __half* gr = G + (size_t)r * 40;
            #pragma unroll
            for (int t = 0; t < 3; ++t) {
                int col = t * 16 + m;
                if (col < 40) gr[col] = __float2half(acc[rt][t][reg]);
            }
        }
    }
}

// 40-dim gather (fp16 in, fp32 out): out[node] = (sum G[src]) * ni + b2p
// 5 lanes per node, one half8 (16 B) each.
__global__ __launch_bounds__(256) void gather40_kernel(
        const __half* __restrict__ G, const int* __restrict__ row_ptr,
        const int* __restrict__ deg, const int* __restrict__ csr_src,
        const float* __restrict__ norm_in, const float* __restrict__ b2p,
        float* __restrict__ out, int n) {
    const int t = blockIdx.x * 256 + threadIdx.x;
    if (t >= n * 5) return;
    const int node = t / 5;
    const int c    = (t - node * 5) * 8;

    const int start = row_ptr[node];
    const int cnt   = deg[node];
    float acc[8] = {0.f, 0.f, 0.f, 0.f, 0.f, 0.f, 0.f, 0.f};

    int j = 0;
    for (; j + 4 <= cnt; j += 4) {
        int s0 = csr_src[start + j];
        int s1 = csr_src[start + j + 1];
        int s2 = csr_src[start + j + 2];
        int s3 = csr_src[start + j + 3];
        half8 v0 = *(const half8*)(G + (long long)s0 * 40 + c);
        half8 v1 = *(const half8*)(G + (long long)s1 * 40 + c);
        half8 v2 = *(const half8*)(G + (long long)s2 * 40 + c);
        half8 v3 = *(const half8*)(G + (long long)s3 * 40 + c);
        #pragma unroll
        for (int k = 0; k < 8; ++k)
            acc[k] += (__half2float(v0.h[k]) + __half2float(v1.h[k]))
                    + (__half2float(v2.h[k]) + __half2float(v3.h[k]));
    }
    for (; j < cnt; ++j) {
        int s0 = csr_src[start + j];
        half8 v0 = *(const half8*)(G + (long long)s0 * 40 + c);
        #pragma unroll
        for (int k = 0; k < 8; ++k) acc[k] += __half2float(v0.h[k]);
    }

    float ni = norm_in[node];
    float4 o0, o1;
    o0.x = acc[0] * ni + b2p[c + 0];
    o0.y = acc[1] * ni + b2p[c + 1];
    o0.z = acc[2] * ni + b2p[c + 2];
    o0.w = acc[3] * ni + b2p[c + 3];
    o1.x = acc[4] * ni + b2p[c + 4];
    o1.y = acc[5] * ni + b2p[c + 5];
    o1.z = acc[6] * ni + b2p[c + 6];
    o1.w = acc[7] * ni + b2p[c + 7];
    float* op = out + (long long)node * 40 + c;
    *(float4*)(op)     = o0;
    *(float4*)(op + 4) = o1;
}

extern "C" void kernel_launch(void* const* d_in, const int* in_sizes, int n_in,
                              void* d_out, int out_size, void* d_ws, size_t ws_size,
                              hipStream_t stream) {
    const float* x   = (const float*)d_in[0];
    const int*   ei  = (const int*)  d_in[1];
    const float* W1  = (const float*)d_in[2];
    const float* b1  = (const float*)d_in[3];
    const float* W2  = (const float*)d_in[4];
    const float* b2  = (const float*)d_in[5];
    const float* Wfc = (const float*)d_in[6];
    const float* bfc = (const float*)d_in[7];
    float* out = (float*)d_out;

    const int N = in_sizes[0] / 128;
    const int E = in_sizes[1] / 2;
    const int* src = ei;
    const int* dst = ei + E;

    const int nbuck = (N + 511) >> 9;                  // 196
    const int B1 = (E + CHUNK - 1) / CHUNK;            // 391 partition blocks

    char* p = (char*)d_ws;
    float* norm_out = (float*)p; p += (size_t)N * 4;
    float* norm_in  = (float*)p; p += (size_t)N * 4;
    float* bufA     = (float*)p; p += (size_t)N * 128 * 4;   // h1pre fp16
    float* bufB     = (float*)p; p += (size_t)N * 128 * 4;   // slabs early, then G fp16
    int*   deg_in   = (int*)p;   p += (size_t)N * 4;
    int*   row_ptr  = (int*)p;   p += (size_t)N * 4;
    int*   csr_src  = (int*)p;   p += (size_t)nbuck * SLAB * 4;   // slab-indexed CSR
    int*   cur_d    = (int*)p;   p += (size_t)1024 * 4;
    int*   cur_s    = (int*)p;   p += (size_t)1024 * 4;
    float* W2p      = (float*)p; p += (size_t)128 * 40 * 4;
    float* b2p      = (float*)p; p += (size_t)64 * 4;

    // partition slabs alias bufB (dead after fine_kernel; G reuses bufB after)
    unsigned int*   ppack  = (unsigned int*)bufB;
    unsigned short* es_loc = (unsigned short*)(ppack + (size_t)nbuck * SLAB);

    __half* h1pre = (__half*)bufA;   // N x 128 fp16
    __half* G     = (__half*)bufB;   // N x 40  fp16 (after slabs are consumed)

    const int T = 256;

    // setup (weight fold + cursor init) runs concurrently-safe first
    setup_kernel<<<(129 * 40 + T - 1) / T, T, 0, stream>>>(
        W2, Wfc, b2, bfc, W2p, b2p, cur_d, cur_s, nbuck);
    // partition + norms
    scatter_res_kernel<<<B1, T, 0, stream>>>(src, dst, cur_d, cur_s, ppack, es_loc, E);
    fine_kernel<<<nbuck, T, 0, stream>>>(ppack, es_loc, cur_d, cur_s,
                                         deg_in, norm_in, row_ptr, csr_src,
                                         norm_out, N);

    // layer 0 GEMM: h1pre = (x * norm_out) @ W1   [MFMA bf16-split]
    const int gemm_grid = (N + 127) / 128;
    gemm128<<<gemm_grid, T, 0, stream>>>(x, norm_out, W1, h1pre, N);

    // fused layer 1+2: gather h1 tile -> relu -> @ W2p -> G
    layer2_fused<<<gemm_grid, T, 0, stream>>>(h1pre, row_ptr, deg_in, csr_src,
                                              norm_in, b1, norm_out, W2p, G, N);

    // final gather: out = gather(G) * ni + b2p
    gather40_kernel<<<((size_t)N * 5 + T - 1) / T, T, 0, stream>>>(
        G, row_ptr, deg_in, csr_src, norm_in, b2p, out, N);
}

// Round 11
// 322.000 us; speedup vs baseline: 1.2232x; 1.2232x over previous
//
#include <hip/hip_runtime.h>
#include <hip/hip_fp16.h>

// ---------------------------------------------------------------------------
// GCN: 2x GraphConv (norm='both') + FC.  fp32 math, fp16 intermediates.
// R2..R8: 5943 -> 325 us (CSR gather, fold FC, MFMA GEMMs, fp16, no atomics).
// R9: reservation partition (323 us).
// R10: gather+gemm fusion REGRESSED (394 us): fusing the latency-bound gather
//      into a 2-block/CU LDS-heavy MFMA kernel cut occupancy 68%->16%. Reverted.
// R11: (a) gather1: 16 lanes x half8 per node - same bytes/coalescing, half
//          the VMEM instructions, 2x nodes/block (probe: issue vs BW bound).
//      (b) CHUNK 4096: 391 partition blocks for CU load balance.
// ---------------------------------------------------------------------------

#define CHUNK    4096   // edges per partition block
#define NB       256    // coarse buckets (node>>9; ceil(100000/512)=196)
#define SLAB     9216   // per-bucket slab capacity (mean 8163 + ~11 sigma)

typedef __attribute__((ext_vector_type(8))) short bf16x8;
typedef __attribute__((ext_vector_type(4))) float f32x4;

struct __align__(8)  half4 { __half x, y, z, w; };
struct __align__(16) half8 { __half h[8]; };

__device__ __forceinline__ unsigned short f2bf(float f) {
    union { float f; unsigned u; } v; v.f = f;
    unsigned r = v.u + 0x7FFFu + ((v.u >> 16) & 1u);   // RNE
    return (unsigned short)(r >> 16);
}
__device__ __forceinline__ float bf2f(unsigned short h) {
    union { unsigned u; float f; } v; v.u = ((unsigned)h) << 16;
    return v.f;
}

// setup: W2p = W2@Wfc, b2p = b2@Wfc + bfc, and slab cursor init
__global__ void setup_kernel(const float* __restrict__ W2, const float* __restrict__ Wfc,
                             const float* __restrict__ b2, const float* __restrict__ bfc,
                             float* __restrict__ W2p, float* __restrict__ b2p,
                             int* __restrict__ cur_d, int* __restrict__ cur_s, int nbuck) {
    int idx = blockIdx.x * blockDim.x + threadIdx.x;
    if (idx < nbuck) { cur_d[idx] = idx * SLAB; cur_s[idx] = idx * SLAB; }
    if (idx < 128 * 40) {
        int k = idx / 40, c = idx - k * 40;
        const float* w2row = W2 + k * 128;
        float a = 0.f;
        #pragma unroll 8
        for (int j = 0; j < 128; ++j) a += w2row[j] * Wfc[j * 40 + c];
        W2p[idx] = a;
    } else if (idx < 129 * 40) {
        int c = idx - 128 * 40;
        float a = bfc[c];
        #pragma unroll 8
        for (int j = 0; j < 128; ++j) a += b2[j] * Wfc[j * 40 + c];
        b2p[c] = a;
    }
}

// ------------- single-pass partition with per-bucket slab reservation -------
__global__ __launch_bounds__(256) void scatter_res_kernel(
        const int* __restrict__ src, const int* __restrict__ dst,
        int* __restrict__ cur_d, int* __restrict__ cur_s,
        unsigned int* __restrict__ ppack, unsigned short* __restrict__ es_loc,
        int E) {
    __shared__ int hd[NB], hs[NB], bd[NB], bs[NB];
    const int tid = threadIdx.x;
    hd[tid] = 0; hs[tid] = 0;
    __syncthreads();
    const int base = blockIdx.x * CHUNK;
    const int end  = min(base + CHUNK, E);
    for (int e = base + tid; e < end; e += 256) {
        atomicAdd(&hd[((unsigned)dst[e]) >> 9], 1);
        atomicAdd(&hs[((unsigned)src[e]) >> 9], 1);
    }
    __syncthreads();
    int cd = hd[tid], cs = hs[tid];
    bd[tid] = cd ? atomicAdd(&cur_d[tid], cd) : 0;
    bs[tid] = cs ? atomicAdd(&cur_s[tid], cs) : 0;
    hd[tid] = 0; hs[tid] = 0;
    __syncthreads();
    for (int e = base + tid; e < end; e += 256) {
        int d = dst[e], s = src[e];
        unsigned bin_d = ((unsigned)d) >> 9;
        int pos = bd[bin_d] + atomicAdd(&hd[bin_d], 1);
        ppack[pos] = (((unsigned)d & 511u) << 17) | (unsigned)s;
        unsigned bin_s = ((unsigned)s) >> 9;
        int ps = bs[bin_s] + atomicAdd(&hs[bin_s], 1);
        es_loc[ps] = (unsigned short)(s & 511);
    }
}

// ------------- per-bucket fine pass for dst (slab ranges) -------------------
__global__ __launch_bounds__(256) void fine_dst_kernel(
        const unsigned int* __restrict__ ppack, const int* __restrict__ cur_d,
        int* __restrict__ deg_in, float* __restrict__ norm_in,
        int* __restrict__ row_ptr, int* __restrict__ csr_src, int N_) {
    __shared__ int h[512];
    __shared__ int psum[256];
    const int tid = threadIdx.x;
    const int b = blockIdx.x;
    const int start = b * SLAB;
    const int end   = cur_d[b];
    const int node0 = b * 512;

    h[tid] = 0; h[tid + 256] = 0;
    __syncthreads();
    for (int i = start + tid; i < end; i += 256)
        atomicAdd(&h[ppack[i] >> 17], 1);
    __syncthreads();

    int a0 = h[2 * tid], a1 = h[2 * tid + 1];
    int pair = a0 + a1;
    psum[tid] = pair;
    __syncthreads();
    for (int off = 1; off < 256; off <<= 1) {
        int t = (tid >= off) ? psum[tid - off] : 0;
        __syncthreads();
        psum[tid] += t;
        __syncthreads();
    }
    int base0 = psum[tid] - pair + start;   // slab-local CSR position

    int n0 = node0 + 2 * tid, n1 = n0 + 1;
    if (n0 < N_) {
        deg_in[n0]  = a0;
        row_ptr[n0] = base0;
        norm_in[n0] = rsqrtf((float)(a0 < 1 ? 1 : a0));
    }
    if (n1 < N_) {
        deg_in[n1]  = a1;
        row_ptr[n1] = base0 + a0;
        norm_in[n1] = rsqrtf((float)(a1 < 1 ? 1 : a1));
    }
    h[2 * tid]     = base0;
    h[2 * tid + 1] = base0 + a0;
    __syncthreads();

    for (int i = start + tid; i < end; i += 256) {
        unsigned int pk = ppack[i];
        int pos = atomicAdd(&h[pk >> 17], 1);
        csr_src[pos] = (int)(pk & 0x1FFFFu);
    }
}

// ------------- per-bucket fine pass for src (norm_out only) -----------------
__global__ __launch_bounds__(256) void fine_src_kernel(
        const unsigned short* __restrict__ es_loc, const int* __restrict__ cur_s,
        float* __restrict__ norm_out, int N_) {
    __shared__ int h[512];
    const int tid = threadIdx.x;
    const int b = blockIdx.x;
    const int start = b * SLAB;
    const int end   = cur_s[b];
    const int node0 = b * 512;

    h[tid] = 0; h[tid + 256] = 0;
    __syncthreads();
    for (int i = start + tid; i < end; i += 256)
        atomicAdd(&h[es_loc[i]], 1);
    __syncthreads();

    int n0 = node0 + tid, n1 = n0 + 256;
    if (n0 < N_) { int d = h[tid];       norm_out[n0] = rsqrtf((float)(d < 1 ? 1 : d)); }
    if (n1 < N_) { int d = h[tid + 256]; norm_out[n1] = rsqrtf((float)(d < 1 ? 1 : d)); }
}

// ---------------------------------------------------------------------------
// Y[nrows x 128] (fp16) = (X * scale[row]) @ W[128x128]  via MFMA bf16 split.
// ---------------------------------------------------------------------------
__global__ __launch_bounds__(256, 2) void gemm128(
        const float* __restrict__ X, const float* __restrict__ scale,
        const float* __restrict__ W, __half* __restrict__ Y, int nrows) {
    __shared__ unsigned short wsh[128 * 128];   // 32 KB, frag-ordered bf16 hi
    __shared__ unsigned short wsl[128 * 128];   // 32 KB, frag-ordered bf16 lo
    const int tid = threadIdx.x;

    for (int i = tid; i < 4096; i += 256) {
        int k  = i >> 5;
        int n0 = (i & 31) * 4;
        float4 wv = *(const float4*)(W + k * 128 + n0);
        int q = k >> 5, j = k & 7, lb = ((k >> 3) & 3) * 16;
        int tcol = n0 >> 4;
        int base = ((tcol * 4 + q) * 64) * 8 + j;
        float vals[4] = {wv.x, wv.y, wv.z, wv.w};
        #pragma unroll
        for (int c = 0; c < 4; ++c) {
            int l = lb + ((n0 + c) & 15);
            unsigned short h = f2bf(vals[c]);
            wsh[base + l * 8] = h;
            wsl[base + l * 8] = f2bf(vals[c] - bf2f(h));
        }
    }
    __syncthreads();

    const int lane = tid & 63;
    const int w    = tid >> 6;
    const int m    = lane & 15;
    const int quad = lane >> 4;
    const int rowBase = blockIdx.x * 128 + w * 32;

    bf16x8 Ah[2][4], Al[2][4];
    #pragma unroll
    for (int rt = 0; rt < 2; ++rt) {
        int r = rowBase + rt * 16 + m;
        float sc = (r < nrows) ? scale[r] : 0.f;
        const float* xr = X + (size_t)(r < nrows ? r : 0) * 128;
        #pragma unroll
        for (int q = 0; q < 4; ++q) {
            int k0 = q * 32 + quad * 8;
            float4 a = *(const float4*)(xr + k0);
            float4 bv = *(const float4*)(xr + k0 + 4);
            float v[8] = {a.x * sc, a.y * sc, a.z * sc, a.w * sc,
                          bv.x * sc, bv.y * sc, bv.z * sc, bv.w * sc};
            bf16x8 hi, lo;
            #pragma unroll
            for (int j = 0; j < 8; ++j) {
                unsigned short h = f2bf(v[j]);
                hi[j] = (short)h;
                lo[j] = (short)f2bf(v[j] - bf2f(h));
            }
            Ah[rt][q] = hi; Al[rt][q] = lo;
        }
    }

    f32x4 acc[2][8];
    #pragma unroll
    for (int rt = 0; rt < 2; ++rt)
        #pragma unroll
        for (int t = 0; t < 8; ++t)
            acc[rt][t] = (f32x4){0.f, 0.f, 0.f, 0.f};

    #pragma unroll
    for (int t = 0; t < 8; ++t) {
        #pragma unroll
        for (int q = 0; q < 4; ++q) {
            const int off = ((t * 4 + q) * 64 + lane) * 8;
            bf16x8 Bh = *(const bf16x8*)(wsh + off);
            bf16x8 Bl = *(const bf16x8*)(wsl + off);
            #pragma unroll
            for (int rt = 0; rt < 2; ++rt) {
                acc[rt][t] = __builtin_amdgcn_mfma_f32_16x16x32_bf16(Ah[rt][q], Bh, acc[rt][t], 0, 0, 0);
                acc[rt][t] = __builtin_amdgcn_mfma_f32_16x16x32_bf16(Ah[rt][q], Bl, acc[rt][t], 0, 0, 0);
                acc[rt][t] = __builtin_amdgcn_mfma_f32_16x16x32_bf16(Al[rt][q], Bh, acc[rt][t], 0, 0, 0);
            }
        }
    }

    #pragma unroll
    for (int rt = 0; rt < 2; ++rt) {
        int r0 = rowBase + rt * 16 + quad * 4;
        #pragma unroll
        for (int reg = 0; reg < 4; ++reg) {
            int r = r0 + reg;
            if (r >= nrows) continue;
            __half* yr = Y + (size_t)r * 128 + m;
            #pragma unroll
            for (int t = 0; t < 8; ++t)
                yr[t * 16] = __float2half(acc[rt][t][reg]);
        }
    }
}

// ---------------------------------------------------------------------------
// G[n x 40] (fp16) = (H[n x 128 fp16] * scale[row]) @ Wp[128 x 40]  via MFMA.
// ---------------------------------------------------------------------------
__global__ __launch_bounds__(256, 2) void gemm40(
        const __half* __restrict__ H, const float* __restrict__ scale,
        const float* __restrict__ Wp, __half* __restrict__ G, int n) {
    __shared__ unsigned short wsh[48 * 128];   // 12 KB, frag-ordered bf16 hi
    __shared__ unsigned short wsl[48 * 128];   // 12 KB, frag-ordered bf16 lo
    const int tid = threadIdx.x;

    for (int i = tid; i < 6144; i += 256) {
        int k  = i / 48;        // 0..127
        int nn = i - k * 48;    // 0..47
        float v = (nn < 40) ? Wp[k * 40 + nn] : 0.f;
        int t = nn >> 4, q = k >> 5, j = k & 7;
        int l = ((k >> 3) & 3) * 16 + (nn & 15);
        int base = ((t * 4 + q) * 64 + l) * 8 + j;
        unsigned short h = f2bf(v);
        wsh[base] = h;
        wsl[base] = f2bf(v - bf2f(h));
    }
    __syncthreads();

    const int lane = tid & 63;
    const int w    = tid >> 6;
    const int m    = lane & 15;
    const int quad = lane >> 4;
    const int rowBase = blockIdx.x * 128 + w * 32;

    bf16x8 Ah[2][4], Al[2][4];
    #pragma unroll
    for (int rt = 0; rt < 2; ++rt) {
        int r = rowBase + rt * 16 + m;
        float sc = (r < n) ? scale[r] : 0.f;
        const __half* xr = H + (size_t)(r < n ? r : 0) * 128;
        #pragma unroll
        for (int q = 0; q < 4; ++q) {
            int k0 = q * 32 + quad * 8;
            half4 a = *(const half4*)(xr + k0);
            half4 bv = *(const half4*)(xr + k0 + 4);
            float v[8] = {__half2float(a.x) * sc, __half2float(a.y) * sc,
                          __half2float(a.z) * sc, __half2float(a.w) * sc,
                          __half2float(bv.x) * sc, __half2float(bv.y) * sc,
                          __half2float(bv.z) * sc, __half2float(bv.w) * sc};
            bf16x8 hi, lo;
            #pragma unroll
            for (int j = 0; j < 8; ++j) {
                unsigned short h = f2bf(v[j]);
                hi[j] = (short)h;
                lo[j] = (short)f2bf(v[j] - bf2f(h));
            }
            Ah[rt][q] = hi; Al[rt][q] = lo;
        }
    }

    f32x4 acc[2][3];
    #pragma unroll
    for (int rt = 0; rt < 2; ++rt)
        #pragma unroll
        for (int t = 0; t < 3; ++t)
            acc[rt][t] = (f32x4){0.f, 0.f, 0.f, 0.f};

    #pragma unroll
    for (int t = 0; t < 3; ++t) {
        #pragma unroll
        for (int q = 0; q < 4; ++q) {
            const int off = ((t * 4 + q) * 64 + lane) * 8;
            bf16x8 Bh = *(const bf16x8*)(wsh + off);
            bf16x8 Bl = *(const bf16x8*)(wsl + off);
            #pragma unroll
            for (int rt = 0; rt < 2; ++rt) {
                acc[rt][t] = __builtin_amdgcn_mfma_f32_16x16x32_bf16(Ah[rt][q], Bh, acc[rt][t], 0, 0, 0);
                acc[rt][t] = __builtin_amdgcn_mfma_f32_16x16x32_bf16(Ah[rt][q], Bl, acc[rt][t], 0, 0, 0);
                acc[rt][t] = __builtin_amdgcn_mfma_f32_16x16x32_bf16(Al[rt][q], Bh, acc[rt][t], 0, 0, 0);
            }
        }
    }

    #pragma unroll
    for (int rt = 0; rt < 2; ++rt) {
        int r0 = rowBase + rt * 16 + quad * 4;
        #pragma unroll
        for (int reg = 0; reg < 4; ++reg) {
            int r = r0 + reg;
            if (r >= n) continue;
            __half* gr = G + (size_t)r * 40;
            #pragma unroll
            for (int t = 0; t < 3; ++t) {
                int col = t * 16 + m;
                if (col < 40) gr[col] = __float2half(acc[rt][t][reg]);
            }
        }
    }
}

// 128-dim gather (fp16 in, fp16 out): h1[node] = relu((sum H[src]) * ni + b)
// 16 lanes per node, one half8 (16 B) per lane; 16 nodes per 256-thread block.
__global__ __launch_bounds__(256) void gather_kernel(
        const __half* __restrict__ H, const int* __restrict__ row_ptr,
        const int* __restrict__ deg, const int* __restrict__ csr_src,
        const float* __restrict__ norm_in, const float* __restrict__ b,
        __half* __restrict__ out, int n) {
    const int tid  = threadIdx.x;
    const int node = blockIdx.x * 16 + (tid >> 4);
    const int c    = (tid & 15) * 8;
    if (node >= n) return;

    const int start = row_ptr[node];
    const int cnt   = deg[node];
    float acc[8] = {0.f, 0.f, 0.f, 0.f, 0.f, 0.f, 0.f, 0.f};

    int j = 0;
    for (; j + 4 <= cnt; j += 4) {
        int s0 = csr_src[start + j];
        int s1 = csr_src[start + j + 1];
        int s2 = csr_src[start + j + 2];
        int s3 = csr_src[start + j + 3];
        half8 v0 = *(const half8*)(H + (long long)s0 * 128 + c);
        half8 v1 = *(const half8*)(H + (long long)s1 * 128 + c);
        half8 v2 = *(const half8*)(H + (long long)s2 * 128 + c);
        half8 v3 = *(const half8*)(H + (long long)s3 * 128 + c);
        #pragma unroll
        for (int k = 0; k < 8; ++k)
            acc[k] += (__half2float(v0.h[k]) + __half2float(v1.h[k]))
                    + (__half2float(v2.h[k]) + __half2float(v3.h[k]));
    }
    for (; j < cnt; ++j) {
        int s0 = csr_src[start + j];
        half8 v0 = *(const half8*)(H + (long long)s0 * 128 + c);
        #pragma unroll
        for (int k = 0; k < 8; ++k) acc[k] += __half2float(v0.h[k]);
    }

    float ni = norm_in[node];
    float4 b0 = *(const float4*)(b + c);
    float4 b1v = *(const float4*)(b + c + 4);
    half8 o;
    o.h[0] = __float2half(fmaxf(acc[0] * ni + b0.x, 0.f));
    o.h[1] = __float2half(fmaxf(acc[1] * ni + b0.y, 0.f));
    o.h[2] = __float2half(fmaxf(acc[2] * ni + b0.z, 0.f));
    o.h[3] = __float2half(fmaxf(acc[3] * ni + b0.w, 0.f));
    o.h[4] = __float2half(fmaxf(acc[4] * ni + b1v.x, 0.f));
    o.h[5] = __float2half(fmaxf(acc[5] * ni + b1v.y, 0.f));
    o.h[6] = __float2half(fmaxf(acc[6] * ni + b1v.z, 0.f));
    o.h[7] = __float2half(fmaxf(acc[7] * ni + b1v.w, 0.f));
    *(half8*)(out + (long long)node * 128 + c) = o;
}

// 40-dim gather (fp16 in, fp32 out): out[node] = (sum G[src]) * ni + b2p
// 5 lanes per node, one half8 (16 B) each.
__global__ __launch_bounds__(256) void gather40_kernel(
        const __half* __restrict__ G, const int* __restrict__ row_ptr,
        const int* __restrict__ deg, const int* __restrict__ csr_src,
        const float* __restrict__ norm_in, const float* __restrict__ b2p,
        float* __restrict__ out, int n) {
    const int t = blockIdx.x * 256 + threadIdx.x;
    if (t >= n * 5) return;
    const int node = t / 5;
    const int c    = (t - node * 5) * 8;

    const int start = row_ptr[node];
    const int cnt   = deg[node];
    float acc[8] = {0.f, 0.f, 0.f, 0.f, 0.f, 0.f, 0.f, 0.f};

    int j = 0;
    for (; j + 4 <= cnt; j += 4) {
        int s0 = csr_src[start + j];
        int s1 = csr_src[start + j + 1];
        int s2 = csr_src[start + j + 2];
        int s3 = csr_src[start + j + 3];
        half8 v0 = *(const half8*)(G + (long long)s0 * 40 + c);
        half8 v1 = *(const half8*)(G + (long long)s1 * 40 + c);
        half8 v2 = *(const half8*)(G + (long long)s2 * 40 + c);
        half8 v3 = *(const half8*)(G + (long long)s3 * 40 + c);
        #pragma unroll
        for (int k = 0; k < 8; ++k)
            acc[k] += (__half2float(v0.h[k]) + __half2float(v1.h[k]))
                    + (__half2float(v2.h[k]) + __half2float(v3.h[k]));
    }
    for (; j < cnt; ++j) {
        int s0 = csr_src[start + j];
        half8 v0 = *(const half8*)(G + (long long)s0 * 40 + c);
        #pragma unroll
        for (int k = 0; k < 8; ++k) acc[k] += __half2float(v0.h[k]);
    }

    float ni = norm_in[node];
    float4 o0, o1;
    o0.x = acc[0] * ni + b2p[c + 0];
    o0.y = acc[1] * ni + b2p[c + 1];
    o0.z = acc[2] * ni + b2p[c + 2];
    o0.w = acc[3] * ni + b2p[c + 3];
    o1.x = acc[4] * ni + b2p[c + 4];
    o1.y = acc[5] * ni + b2p[c + 5];
    o1.z = acc[6] * ni + b2p[c + 6];
    o1.w = acc[7] * ni + b2p[c + 7];
    float* op = out + (long long)node * 40 + c;
    *(float4*)(op)     = o0;
    *(float4*)(op + 4) = o1;
}

extern "C" void kernel_launch(void* const* d_in, const int* in_sizes, int n_in,
                              void* d_out, int out_size, void* d_ws, size_t ws_size,
                              hipStream_t stream) {
    const float* x   = (const float*)d_in[0];
    const int*   ei  = (const int*)  d_in[1];
    const float* W1  = (const float*)d_in[2];
    const float* b1  = (const float*)d_in[3];
    const float* W2  = (const float*)d_in[4];
    const float* b2  = (const float*)d_in[5];
    const float* Wfc = (const float*)d_in[6];
    const float* bfc = (const float*)d_in[7];
    float* out = (float*)d_out;

    const int N = in_sizes[0] / 128;
    const int E = in_sizes[1] / 2;
    const int* src = ei;
    const int* dst = ei + E;

    const int nbuck = (N + 511) >> 9;                  // 196
    const int B1 = (E + CHUNK - 1) / CHUNK;            // 391 partition blocks

    char* p = (char*)d_ws;
    float* norm_out = (float*)p; p += (size_t)N * 4;
    float* norm_in  = (float*)p; p += (size_t)N * 4;
    float* bufA     = (float*)p; p += (size_t)N * 128 * 4;   // h1pre fp16, then G fp16
    float* bufB     = (float*)p; p += (size_t)N * 128 * 4;   // h1 fp16 (early: slabs)
    int*   deg_in   = (int*)p;   p += (size_t)N * 4;
    int*   row_ptr  = (int*)p;   p += (size_t)N * 4;
    int*   csr_src  = (int*)p;   p += (size_t)nbuck * SLAB * 4;   // slab-indexed CSR
    int*   cur_d    = (int*)p;   p += (size_t)1024 * 4;
    int*   cur_s    = (int*)p;   p += (size_t)1024 * 4;
    float* W2p      = (float*)p; p += (size_t)128 * 40 * 4;
    float* b2p      = (float*)p; p += (size_t)64 * 4;

    // partition slabs alias bufB (consumed before gather writes h1 there)
    unsigned int*   ppack  = (unsigned int*)bufB;
    unsigned short* es_loc = (unsigned short*)(ppack + (size_t)nbuck * SLAB);

    __half* h1pre = (__half*)bufA;   // N x 128 fp16
    __half* G     = (__half*)bufA;   // N x 40  fp16 (reused after gather1)
    __half* h1    = (__half*)bufB;   // N x 128 fp16

    const int T = 256;

    // setup (weight fold + cursor init)
    setup_kernel<<<(129 * 40 + T - 1) / T, T, 0, stream>>>(
        W2, Wfc, b2, bfc, W2p, b2p, cur_d, cur_s, nbuck);
    // partition + norms
    scatter_res_kernel<<<B1, T, 0, stream>>>(src, dst, cur_d, cur_s, ppack, es_loc, E);
    fine_dst_kernel<<<nbuck, T, 0, stream>>>(ppack, cur_d, deg_in, norm_in,
                                             row_ptr, csr_src, N);
    fine_src_kernel<<<nbuck, T, 0, stream>>>(es_loc, cur_s, norm_out, N);

    // layer 0: h1 = relu(gather(Xn @ W1) * ni + b1)   [MFMA bf16-split GEMM]
    const int gemm_grid = (N + 127) / 128;
    gemm128<<<gemm_grid, T, 0, stream>>>(x, norm_out, W1, h1pre, N);
    const int gather_grid = (N + 15) / 16;
    gather_kernel<<<gather_grid, T, 0, stream>>>(h1pre, row_ptr, deg_in, csr_src,
                                                 norm_in, b1, h1, N);
    // layer 1 + FC fused: out = gather((h1*no) @ W2p) * ni + b2p  [MFMA]
    gemm40<<<gemm_grid, T, 0, stream>>>(h1, norm_out, W2p, G, N);
    gather40_kernel<<<((size_t)N * 5 + T - 1) / T, T, 0, stream>>>(
        G, row_ptr, deg_in, csr_src, norm_in, b2p, out, N);
}